// Round 15
// baseline (273.709 us; speedup 1.0000x reference)
//
#include <hip/hip_runtime.h>
#include <hip/hip_bf16.h>

#define NN 50000
#define EE 400000
#define EP 450000   // EE + NN self-loops

typedef __attribute__((ext_vector_type(8))) short short8;
typedef __attribute__((ext_vector_type(4))) float f32x4;
typedef __attribute__((ext_vector_type(2))) float f32x2;

__device__ __forceinline__ float us2f(unsigned short u) {
    unsigned int x = ((unsigned int)u) << 16;
    union { unsigned int i; float f; } c; c.i = x; return c.f;
}
__device__ __forceinline__ unsigned short f2bfu(float f) {   // f32 -> bf16 bits, RNE
    union { float f; unsigned int u; } c; c.f = f;
    unsigned int r = c.u + 0x7FFFu + ((c.u >> 16) & 1u);
    return (unsigned short)(r >> 16);
}
__device__ __forceinline__ unsigned int pack2bf(float lo, float hi) {
    return (unsigned int)f2bfu(lo) | ((unsigned int)f2bfu(hi) << 16);
}
__device__ __forceinline__ float lrelu_exp(float x) {
    x = x > 0.f ? x : 0.2f * x;
    return __expf(x);
}

// Packed MFMA-fragment index for a [M x K] bf16 matrix consumed as A (or B with
// n in place of m) by mfma_f32_16x16x32_bf16:
//   idx(m,k) = ((m>>4)*(K/32) + (k>>5))*512 + ((k&31)>>3)*128 + (m&15)*8 + (k&7)

// ---------------------------------------------------------------------------
// prep: fused deg histogram + W1/W2 f32->bf16 packed convert + usd precompute.
// ---------------------------------------------------------------------------
#define DEGB 1758
#define CVTB 512
__global__ void prep_kernel(const int* __restrict__ ei, int* __restrict__ deg,
                            const float* __restrict__ W1, const float* __restrict__ W2,
                            __hip_bfloat16* __restrict__ pw1, __hip_bfloat16* __restrict__ pw2,
                            const float* __restrict__ a1s, const float* __restrict__ a1d,
                            float* __restrict__ usd) {
    int b = blockIdx.x;
    if (b < DEGB) {
        int e = b * 256 + threadIdx.x;
        if (e >= EP) return;
        int dst = (e < EE) ? ei[EE + e] : e - EE;
        atomicAdd(&deg[dst], 1);
    } else if (b < DEGB + CVTB) {
        int i = (b - DEGB) * 256 + threadIdx.x;
        if (i < 65536) {
            int n = i >> 7, k = i & 127;   // K=128, NK=4
            int idx = ((n >> 4) * 4 + (k >> 5)) * 512 + ((k & 31) >> 3) * 128 + (n & 15) * 8 + (k & 7);
            pw1[idx] = __float2bfloat16(W1[i]);
        } else {
            int j = i - 65536;
            int n = j >> 9, k = j & 511;   // K=512, NK=16
            int idx = ((n >> 4) * 16 + (k >> 5)) * 512 + ((k & 31) >> 3) * 128 + (n & 15) * 8 + (k & 7);
            pw2[idx] = __float2bfloat16(W2[j]);
        }
    } else {
        int t = (b - DEGB - CVTB) * 256 + threadIdx.x;
        if (t >= 1024) return;
        int row = t >> 7, k = t & 127;
        int hh = row & 3;
        const float* av = (row < 4) ? (a1s + hh * 128) : (a1d + hh * 128);
        const float* wp = W1 + (size_t)(hh * 128) * 128 + k;
        float acc = 0.f;
        for (int c = 0; c < 128; c++) acc += av[c] * wp[(size_t)c * 128];
        usd[t] = acc;
    }
}

// ---------------------------------------------------------------------------
// Fused: x (f32) -> xb (bf16) convert + s1/d1 = x . usd.
// ---------------------------------------------------------------------------
__global__ void cvtx_sd(const float* __restrict__ x, const float* __restrict__ usd,
                        __hip_bfloat16* __restrict__ xb,
                        float* __restrict__ s, float* __restrict__ d, int M) {
    __shared__ float us_s[1024];
    for (int i = threadIdx.x; i < 1024; i += 256) us_s[i] = usd[i];
    __syncthreads();
    int wave = threadIdx.x >> 6, lane = threadIdx.x & 63;
    int m0 = blockIdx.x * 64 + wave * 16;
    int r = lane & 15, quad = lane >> 4;
    int am = m0 + r; if (am >= M) am = M - 1;
    const float* xp = x + (size_t)am * 128 + quad * 8;
    float xv[32];
#pragma unroll
    for (int kk = 0; kk < 4; kk++) {
        float4 a = *(const float4*)(xp + kk * 32);
        float4 bq = *(const float4*)(xp + kk * 32 + 4);
        xv[kk*8+0]=a.x;  xv[kk*8+1]=a.y;  xv[kk*8+2]=a.z;  xv[kk*8+3]=a.w;
        xv[kk*8+4]=bq.x; xv[kk*8+5]=bq.y; xv[kk*8+6]=bq.z; xv[kk*8+7]=bq.w;
        short8 o;
        o[0]=(short)f2bfu(a.x);  o[1]=(short)f2bfu(a.y);
        o[2]=(short)f2bfu(a.z);  o[3]=(short)f2bfu(a.w);
        o[4]=(short)f2bfu(bq.x); o[5]=(short)f2bfu(bq.y);
        o[6]=(short)f2bfu(bq.z); o[7]=(short)f2bfu(bq.w);
        *(short8*)(xb + (size_t)am * 128 + quad * 8 + kk * 32) = o;
    }
    float acc[8];
#pragma unroll
    for (int o = 0; o < 8; o++) {
        const float* up = us_s + o * 128 + quad * 8;
        float a = 0.f;
#pragma unroll
        for (int kk = 0; kk < 4; kk++)
#pragma unroll
            for (int j = 0; j < 8; j++) a += xv[kk*8+j] * up[kk*32+j];
        acc[o] = a;
    }
#pragma unroll
    for (int o = 0; o < 8; o++) {
        acc[o] += __shfl_xor(acc[o], 16, 64);
        acc[o] += __shfl_xor(acc[o], 32, 64);
    }
    int m = m0 + r;
    if (quad == 0 && m < M) {
#pragma unroll
        for (int hh = 0; hh < 4; hh++) { s[m*4+hh] = acc[hh]; d[m*4+hh] = acc[4+hh]; }
    }
}

// ---------------------------------------------------------------------------
// Two-level multi-block scan of deg -> offsets
// ---------------------------------------------------------------------------
#define SCB 49
__global__ void scan1_kernel(const int* __restrict__ deg, int* __restrict__ bsum) {
    __shared__ int red[256];
    int b = blockIdx.x, t = threadIdx.x;
    int base = b * 1024 + t * 4;
    int s = 0;
    if (base + 3 < NN) { int4 v = *(const int4*)(deg + base); s = v.x + v.y + v.z + v.w; }
    else { for (int i = base; i < NN; i++) s += deg[i]; }
    red[t] = s;
    __syncthreads();
    for (int off = 128; off > 0; off >>= 1) {
        if (t < off) red[t] += red[t + off];
        __syncthreads();
    }
    if (t == 0) bsum[b] = red[0];
}

__global__ void scan2_kernel(const int* __restrict__ deg, const int* __restrict__ bsum,
                             int* __restrict__ offsets) {
    __shared__ int lsum[256];
    int b = blockIdx.x, t = threadIdx.x;
    int boff = 0;
    for (int i = 0; i < b; i++) boff += bsum[i];
    int base = b * 1024 + t * 4;
    int4 v = {0, 0, 0, 0};
    if (base + 3 < NN) v = *(const int4*)(deg + base);
    else {
        if (base < NN)     v.x = deg[base];
        if (base + 1 < NN) v.y = deg[base + 1];
        if (base + 2 < NN) v.z = deg[base + 2];
        if (base + 3 < NN) v.w = deg[base + 3];
    }
    int s = v.x + v.y + v.z + v.w;
    lsum[t] = s;
    __syncthreads();
    for (int off = 1; off < 256; off <<= 1) {
        int val = (t >= off) ? lsum[t - off] : 0;
        __syncthreads();
        lsum[t] += val;
        __syncthreads();
    }
    int ex = boff + (t ? lsum[t - 1] : 0);
    if (base < NN)     offsets[base]     = ex;
    if (base + 1 < NN) offsets[base + 1] = ex + v.x;
    if (base + 2 < NN) offsets[base + 2] = ex + v.x + v.y;
    if (base + 3 < NN) offsets[base + 3] = ex + v.x + v.y + v.z;
    if (b == SCB - 1 && t == 255) offsets[NN] = boff + lsum[255];
}

// ---------------------------------------------------------------------------
// fill: CSR scatter + fused layer-1 edge weights (s1/d1 already computed).
// ---------------------------------------------------------------------------
__global__ void fill_kernel(const int* __restrict__ ei, const int* __restrict__ offsets,
                            int* __restrict__ cursor,
                            const float* __restrict__ s1, const float* __restrict__ d1,
                            int* __restrict__ elist, float* __restrict__ welist) {
    int e = blockIdx.x * blockDim.x + threadIdx.x;
    if (e >= EP) return;
    int src, dst;
    if (e < EE) { src = ei[e]; dst = ei[EE + e]; } else { src = dst = e - EE; }
    int pos = atomicAdd(&cursor[dst], 1);
    int j = offsets[dst] + pos;
    elist[j] = src;
    float4 sv = *(const float4*)(s1 + (size_t)src * 4);
    float4 dv = *(const float4*)(d1 + (size_t)dst * 4);
    float4 w;
    w.x = lrelu_exp(sv.x + dv.x);
    w.y = lrelu_exp(sv.y + dv.y);
    w.z = lrelu_exp(sv.z + dv.z);
    w.w = lrelu_exp(sv.w + dv.w);
    *(float4*)(welist + (size_t)j * 4) = w;
}

// ---------------------------------------------------------------------------
// Edge accumulate, packed over HEAD PAIRS (w01 = heads 0-1, w23 = heads 2-3):
// acc[0]=c0/h01, acc[1]=c0/h23, acc[2]=c1/h01, acc[3]=c1/h23.
// Plain vector C — clang emits v_pk_fma_f32 / v_pk_add_f32 on gfx950.
// ---------------------------------------------------------------------------
__device__ __forceinline__ void acc_edge(f32x2& den01, f32x2& den23, f32x2 (&acc)[4],
                                         float4 w, unsigned int x) {
    float x0 = us2f((unsigned short)x), x1 = us2f((unsigned short)(x >> 16));
    f32x2 w01; w01[0] = w.x; w01[1] = w.y;
    f32x2 w23; w23[0] = w.z; w23[1] = w.w;
    f32x2 x0s; x0s[0] = x0; x0s[1] = x0;
    f32x2 x1s; x1s[0] = x1; x1s[1] = x1;
    acc[0] += w01 * x0s;
    acc[1] += w23 * x0s;
    acc[2] += w01 * x1s;
    acc[3] += w23 * x1s;
    den01 += w01;
    den23 += w23;
}

// ---------------------------------------------------------------------------
// Layer-1+2 FUSED: gather + bdiag GEMM (LDS) + layer-2 GEMM. 512 thr = 8 waves.
// LDS: ONE 16.6 KB buffer. act1 ALIASES frag: phase 2 loads afrag to registers
// first, then a barrier, then writes act1 in place. Wave (hh,half) writes only
// k-tiles 4hh+2half+{0,1} — a subset of its own head's read region [4hh,4hh+4),
// disjoint across heads/halves, so the in-place reuse is race-free.
// Phase 0: degree-sorted pairing (rank w with rank 15-w).
// Phase 1: dual-pointer gather, 4+4 edges in flight, packed-FMA accumulate.
// Phase 2: wave (head,half): afrag regs -> barrier -> 4 n-tiles x 4 MFMA,
//          ELU -> act1 (in-place, packed K=512 layout, same swizzle).
// Phase 3: waves 0-3 (= head): layer-2 GEMM from act1 + packed W2,
//          h2 row-major -> global, fused s2/d2 butterfly epilogue.
// ---------------------------------------------------------------------------
__global__ void l1_fused(
        const int* __restrict__ elist, const int* __restrict__ offsets,
        const float* __restrict__ wl,
        const __hip_bfloat16* __restrict__ xb,
        const __hip_bfloat16* __restrict__ pW1,
        const float* __restrict__ b,
        const __hip_bfloat16* __restrict__ pW2,
        const float* __restrict__ as_, const float* __restrict__ ad_,
        __hip_bfloat16* __restrict__ h2,
        float* __restrict__ s2, float* __restrict__ d2) {
    __shared__ unsigned short frag[16 * 520];          // 16.6 KB (act1 aliases)
    unsigned short* act1 = frag;
    int w = threadIdx.x >> 6, lane = threadIdx.x & 63;
    int m0 = blockIdx.x * 16;

    // ---- phase 0: degree-sorted pairing (redundant per wave, no barrier) ----
    int li = lane < 16 ? lane : 15;
    int mydeg = offsets[m0 + li + 1] - offsets[m0 + li];
    int rank = 0;
#pragma unroll
    for (int jj = 0; jj < 16; jj++) {
        int od = __shfl(mydeg, jj, 64);
        rank += (od < mydeg) || (od == mydeg && jj < li);
    }
    unsigned long long balA = __ballot(lane < 16 && rank == w);
    unsigned long long balB = __ballot(lane < 16 && rank == 15 - w);
    int iA = (int)__builtin_ctzll(balA);
    int iB = (int)__builtin_ctzll(balB);
    int nodeA = m0 + iA, nodeB = m0 + iB;

    int ja  = __builtin_amdgcn_readfirstlane(offsets[nodeA]);
    int jA1 = __builtin_amdgcn_readfirstlane(offsets[nodeA + 1]);
    int jb  = __builtin_amdgcn_readfirstlane(offsets[nodeB]);
    int jB1 = __builtin_amdgcn_readfirstlane(offsets[nodeB + 1]);

    f32x2 dA01, dA23, dB01, dB23;
    dA01[0]=0.f; dA01[1]=0.f; dA23[0]=0.f; dA23[1]=0.f;
    dB01[0]=0.f; dB01[1]=0.f; dB23[0]=0.f; dB23[1]=0.f;
    f32x2 aA[4], aB[4];
#pragma unroll
    for (int h = 0; h < 4; h++) {
        aA[h][0]=0.f; aA[h][1]=0.f;
        aB[h][0]=0.f; aB[h][1]=0.f;
    }
    const unsigned short* xp = (const unsigned short*)xb + lane * 2;
    const float4* wl4 = (const float4*)wl;

    // 4+4 deep-pipelined main loop: 8 x-loads in flight
    while (ja + 4 <= jA1 && jb + 4 <= jB1) {
        int sA0 = elist[ja],   sA1 = elist[ja+1], sA2 = elist[ja+2], sA3 = elist[ja+3];
        int sB0 = elist[jb],   sB1 = elist[jb+1], sB2 = elist[jb+2], sB3 = elist[jb+3];
        float4 wA0 = wl4[ja],   wA1 = wl4[ja+1], wA2 = wl4[ja+2], wA3 = wl4[ja+3];
        float4 wB0 = wl4[jb],   wB1 = wl4[jb+1], wB2 = wl4[jb+2], wB3 = wl4[jb+3];
        unsigned int xA0 = *(const unsigned int*)(xp + (size_t)sA0 * 128);
        unsigned int xA1 = *(const unsigned int*)(xp + (size_t)sA1 * 128);
        unsigned int xA2 = *(const unsigned int*)(xp + (size_t)sA2 * 128);
        unsigned int xA3 = *(const unsigned int*)(xp + (size_t)sA3 * 128);
        unsigned int xB0 = *(const unsigned int*)(xp + (size_t)sB0 * 128);
        unsigned int xB1 = *(const unsigned int*)(xp + (size_t)sB1 * 128);
        unsigned int xB2 = *(const unsigned int*)(xp + (size_t)sB2 * 128);
        unsigned int xB3 = *(const unsigned int*)(xp + (size_t)sB3 * 128);
        acc_edge(dA01, dA23, aA, wA0, xA0); acc_edge(dA01, dA23, aA, wA1, xA1);
        acc_edge(dA01, dA23, aA, wA2, xA2); acc_edge(dA01, dA23, aA, wA3, xA3);
        acc_edge(dB01, dB23, aB, wB0, xB0); acc_edge(dB01, dB23, aB, wB1, xB1);
        acc_edge(dB01, dB23, aB, wB2, xB2); acc_edge(dB01, dB23, aB, wB3, xB3);
        ja += 4; jb += 4;
    }
    // 2+2 drain
    while (ja + 2 <= jA1 && jb + 2 <= jB1) {
        int sA0 = elist[ja], sA1 = elist[ja + 1];
        int sB0 = elist[jb], sB1 = elist[jb + 1];
        float4 wA0 = wl4[ja], wA1 = wl4[ja + 1];
        float4 wB0 = wl4[jb], wB1 = wl4[jb + 1];
        unsigned int xA0 = *(const unsigned int*)(xp + (size_t)sA0 * 128);
        unsigned int xA1 = *(const unsigned int*)(xp + (size_t)sA1 * 128);
        unsigned int xB0 = *(const unsigned int*)(xp + (size_t)sB0 * 128);
        unsigned int xB1 = *(const unsigned int*)(xp + (size_t)sB1 * 128);
        acc_edge(dA01, dA23, aA, wA0, xA0); acc_edge(dA01, dA23, aA, wA1, xA1);
        acc_edge(dB01, dB23, aB, wB0, xB0); acc_edge(dB01, dB23, aB, wB1, xB1);
        ja += 2; jb += 2;
    }
    while (ja + 2 <= jA1) {
        int sA0 = elist[ja], sA1 = elist[ja + 1];
        float4 wA0 = wl4[ja], wA1 = wl4[ja + 1];
        unsigned int xA0 = *(const unsigned int*)(xp + (size_t)sA0 * 128);
        unsigned int xA1 = *(const unsigned int*)(xp + (size_t)sA1 * 128);
        acc_edge(dA01, dA23, aA, wA0, xA0); acc_edge(dA01, dA23, aA, wA1, xA1);
        ja += 2;
    }
    while (jb + 2 <= jB1) {
        int sB0 = elist[jb], sB1 = elist[jb + 1];
        float4 wB0 = wl4[jb], wB1 = wl4[jb + 1];
        unsigned int xB0 = *(const unsigned int*)(xp + (size_t)sB0 * 128);
        unsigned int xB1 = *(const unsigned int*)(xp + (size_t)sB1 * 128);
        acc_edge(dB01, dB23, aB, wB0, xB0); acc_edge(dB01, dB23, aB, wB1, xB1);
        jb += 2;
    }
    if (ja < jA1) {
        int sA0 = elist[ja]; float4 wA0 = wl4[ja];
        unsigned int xA0 = *(const unsigned int*)(xp + (size_t)sA0 * 128);
        acc_edge(dA01, dA23, aA, wA0, xA0);
    }
    if (jb < jB1) {
        int sB0 = elist[jb]; float4 wB0 = wl4[jb];
        unsigned int xB0 = *(const unsigned int*)(xp + (size_t)sB0 * 128);
        acc_edge(dB01, dB23, aB, wB0, xB0);
    }

    // store both nodes' normalized fragments to LDS (swizzled)
    // acc layout: [0]=c0/h01 [1]=c0/h23 [2]=c1/h01 [3]=c1/h23
    {
        int c0 = lane * 2;
        int fq = c0 >> 5;
        int sub = (c0 & 31) >> 3;
        unsigned int* f32p = (unsigned int*)frag;
        int base0 = fq * 260 + sub * 64 + (c0 & 7) / 2;   // uint units
        {
            int rowp = iA ^ (sub << 2);
            int base = base0 + rowp * 4;
            float i0 = 1.f/dA01[0], i1 = 1.f/dA01[1], i2 = 1.f/dA23[0], i3 = 1.f/dA23[1];
            f32p[base]            = pack2bf(aA[0][0]*i0, aA[2][0]*i0);   // head0: c0,c1
            f32p[base + 4 * 260]  = pack2bf(aA[0][1]*i1, aA[2][1]*i1);   // head1
            f32p[base + 8 * 260]  = pack2bf(aA[1][0]*i2, aA[3][0]*i2);   // head2
            f32p[base + 12 * 260] = pack2bf(aA[1][1]*i3, aA[3][1]*i3);   // head3
        }
        {
            int rowp = iB ^ (sub << 2);
            int base = base0 + rowp * 4;
            float i0 = 1.f/dB01[0], i1 = 1.f/dB01[1], i2 = 1.f/dB23[0], i3 = 1.f/dB23[1];
            f32p[base]            = pack2bf(aB[0][0]*i0, aB[2][0]*i0);
            f32p[base + 4 * 260]  = pack2bf(aB[0][1]*i1, aB[2][1]*i1);
            f32p[base + 8 * 260]  = pack2bf(aB[1][0]*i2, aB[3][0]*i2);
            f32p[base + 12 * 260] = pack2bf(aB[1][1]*i3, aB[3][1]*i3);
        }
    }
    __syncthreads();

    // ---- phase 2: block-diagonal GEMM from LDS -> act1 IN PLACE ----
    int hh = w >> 1, half = w & 1;
    int r = lane & 15, quad = lane >> 4;
    int lsub = lane >> 4, lrow = lane & 15;
    int prow = lrow ^ (lsub << 2);
    {
        const unsigned short* fb = frag + lsub * 128 + prow * 8;
        short8 afrag[4];
#pragma unroll
        for (int kk = 0; kk < 4; kk++)
            afrag[kk] = *(const short8*)(fb + (hh * 4 + kk) * 520);
        __syncthreads();   // all afrag loads done before in-place act1 writes
#pragma unroll
        for (int t = 0; t < 4; t++) {
            int nb = half * 64 + t * 16;
            const __hip_bfloat16* bp = pW1 + ((size_t)(hh * 8 + (nb >> 4)) * 4) * 512 + lane * 8;
            f32x4 acc = {0.f, 0.f, 0.f, 0.f};
#pragma unroll
            for (int kk = 0; kk < 4; kk++) {
                short8 bfr = *(const short8*)(bp + kk * 512);
                acc = __builtin_amdgcn_mfma_f32_16x16x32_bf16(afrag[kk], bfr, acc, 0, 0, 0);
            }
            int n0 = hh * 128 + nb;
            float bias = b[n0 + r];
            int kk2 = (n0 + r) >> 5;                 // k-tile in K=512 layout
            int sub2 = ((nb & 16) + r) >> 3;         // k-subgroup
#pragma unroll
            for (int i = 0; i < 4; i++) {
                float v = acc[i] + bias;
                v = v > 0.f ? v : (__expf(v) - 1.0f);
                int rowp2 = (quad * 4 + i) ^ (sub2 << 2);
                act1[kk2 * 520 + sub2 * 128 + rowp2 * 8 + (r & 7)] = f2bfu(v);
            }
        }
    }
    __syncthreads();

    // ---- phase 3: layer-2 GEMM from act1 LDS (waves 0-3, wave = head) ----
    if (w < 4) {
        int h2h = w;                                 // head 0..3
        const __hip_bfloat16* bp0 = pW2 + (size_t)(h2h * 2) * 16 * 512 + lane * 8;
        const __hip_bfloat16* bp1 = bp0 + 16 * 512;
        const unsigned short* ab = act1 + lsub * 128 + prow * 8;
        f32x4 acc0 = {0.f, 0.f, 0.f, 0.f}, acc1 = {0.f, 0.f, 0.f, 0.f};
#pragma unroll
        for (int kk = 0; kk < 16; kk++) {
            short8 af = *(const short8*)(ab + kk * 520);
            short8 b0 = *(const short8*)(bp0 + kk * 512);
            short8 b1 = *(const short8*)(bp1 + kk * 512);
            acc0 = __builtin_amdgcn_mfma_f32_16x16x32_bf16(af, b0, acc0, 0, 0, 0);
            acc1 = __builtin_amdgcn_mfma_f32_16x16x32_bf16(af, b1, acc1, 0, 0, 0);
        }
        int n0 = h2h * 32;
        float as0 = as_[n0 + r],      ad0 = ad_[n0 + r];
        float as1 = as_[n0 + 16 + r], ad1 = ad_[n0 + 16 + r];
        float sacc[4], dacc[4];
#pragma unroll
        for (int i = 0; i < 4; i++) {
            int m = m0 + quad * 4 + i;
            h2[(size_t)m * 128 + n0 + r]      = __float2bfloat16(acc0[i]);
            h2[(size_t)m * 128 + n0 + 16 + r] = __float2bfloat16(acc1[i]);
            sacc[i] = acc0[i] * as0 + acc1[i] * as1;
            dacc[i] = acc0[i] * ad0 + acc1[i] * ad1;
        }
#pragma unroll
        for (int mask = 1; mask <= 8; mask <<= 1) {
#pragma unroll
            for (int i = 0; i < 4; i++) {
                sacc[i] += __shfl_xor(sacc[i], mask, 64);
                dacc[i] += __shfl_xor(dacc[i], mask, 64);
            }
        }
        if (r == 0) {
#pragma unroll
            for (int i = 0; i < 4; i++) {
                int m = m0 + quad * 4 + i;
                s2[m * 4 + h2h] = sacc[i]; d2[m * 4 + h2h] = dacc[i];
            }
        }
    }
}

// ---------------------------------------------------------------------------
// Layer-2 gather FUSED with layer-3 GEMM: node-per-wave; lane owns 2 h2
// channels. Edge weights computed INLINE from s2/d2.
// L3 GEMM uses recursive-halving reduce; lane's group (bits 5:4:3) -> output o.
// ---------------------------------------------------------------------------
__global__ void gather_l2_g8(const int* __restrict__ elist, const int* __restrict__ offsets,
                             const float* __restrict__ s2, const float* __restrict__ d2,
                             const __hip_bfloat16* __restrict__ h,
                             const float* __restrict__ b,
                             const float* __restrict__ W3,
                             const float* __restrict__ a3s, const float* __restrict__ a3d,
                             __hip_bfloat16* __restrict__ h3,
                             float* __restrict__ s3, float* __restrict__ d3) {
    int gid = blockIdx.x * blockDim.x + threadIdx.x;
    if (gid >= NN * 64) return;
    int node = gid >> 6;
    int lane = gid & 63;
    int c0 = lane * 2;
    int hh = lane >> 4;
    int j0 = __builtin_amdgcn_readfirstlane(offsets[node]);
    int j1 = __builtin_amdgcn_readfirstlane(offsets[node + 1]);
    float dv = d2[node * 4 + hh];
    float den = 0.f, acc0 = 0.f, acc1 = 0.f;
    const unsigned short* hp = (const unsigned short*)h + c0;
    int j = j0;
    for (; j + 4 <= j1; j += 4) {
        int sA = elist[j], sB = elist[j+1], sC = elist[j+2], sD = elist[j+3];
        float eA = s2[sA * 4 + hh] + dv, eB = s2[sB * 4 + hh] + dv;
        float eC = s2[sC * 4 + hh] + dv, eD = s2[sD * 4 + hh] + dv;
        unsigned int vA = *(const unsigned int*)(hp + (size_t)sA * 128);
        unsigned int vB = *(const unsigned int*)(hp + (size_t)sB * 128);
        unsigned int vC = *(const unsigned int*)(hp + (size_t)sC * 128);
        unsigned int vD = *(const unsigned int*)(hp + (size_t)sD * 128);
        float wA = lrelu_exp(eA), wB = lrelu_exp(eB);
        float wC = lrelu_exp(eC), wD = lrelu_exp(eD);
        den += (wA + wB) + (wC + wD);
        acc0 += wA * us2f((unsigned short)vA) + wB * us2f((unsigned short)vB)
              + wC * us2f((unsigned short)vC) + wD * us2f((unsigned short)vD);
        acc1 += wA * us2f((unsigned short)(vA >> 16)) + wB * us2f((unsigned short)(vB >> 16))
              + wC * us2f((unsigned short)(vC >> 16)) + wD * us2f((unsigned short)(vD >> 16));
    }
    for (; j < j1; j++) {
        int sE = elist[j];
        float ww = lrelu_exp(s2[sE * 4 + hh] + dv);
        unsigned int v = *(const unsigned int*)(hp + (size_t)sE * 128);
        den += ww;
        acc0 += ww * us2f((unsigned short)v);
        acc1 += ww * us2f((unsigned short)(v >> 16));
    }
    float inv = 1.0f / den;
    float v0 = acc0 * inv + b[c0];
    float v1 = acc1 * inv + b[c0 + 1];
    v0 = v0 > 0.f ? v0 : (__expf(v0) - 1.0f);
    v1 = v1 > 0.f ? v1 : (__expf(v1) - 1.0f);
    // fused layer-3 GEMM: partial over this lane's 2 channels
    float part[8];
#pragma unroll
    for (int c = 0; c < 8; c++) {
        float2 wv = *(const float2*)(W3 + c * 128 + c0);
        part[c] = v0 * wv.x + v1 * wv.y;
    }
    // recursive-halving reduce-scatter: 8 -> 4 -> 2 -> 1 values
    float t4[4];
#pragma unroll
    for (int i = 0; i < 4; i++) {
        float send = (lane & 32) ? part[i] : part[4 + i];
        float keep = (lane & 32) ? part[4 + i] : part[i];
        t4[i] = keep + __shfl_xor(send, 32, 64);
    }
    float t2[2];
#pragma unroll
    for (int i = 0; i < 2; i++) {
        float send = (lane & 16) ? t4[i] : t4[2 + i];
        float keep = (lane & 16) ? t4[2 + i] : t4[i];
        t2[i] = keep + __shfl_xor(send, 16, 64);
    }
    float gv;
    {
        float send = (lane & 8) ? t2[0] : t2[1];
        float keep = (lane & 8) ? t2[1] : t2[0];
        gv = keep + __shfl_xor(send, 8, 64);
    }
    gv += __shfl_xor(gv, 4, 64);
    gv += __shfl_xor(gv, 2, 64);
    gv += __shfl_xor(gv, 1, 64);
    int o = ((lane >> 5) & 1) * 4 + ((lane >> 4) & 1) * 2 + ((lane >> 3) & 1);
    if ((lane & 7) == 0) h3[(size_t)node * 8 + o] = __float2bfloat16(gv);
    // s3/d3: sum over the 8 groups (masks 8/16/32 only -> each group once)
    float cs = gv * a3s[o];
    float cd = gv * a3d[o];
    cs += __shfl_xor(cs, 8, 64);  cd += __shfl_xor(cd, 8, 64);
    cs += __shfl_xor(cs, 16, 64); cd += __shfl_xor(cd, 16, 64);
    cs += __shfl_xor(cs, 32, 64); cd += __shfl_xor(cd, 32, 64);
    if (lane == 0) { s3[node] = cs; d3[node] = cd; }
}

// ---------------------------------------------------------------------------
// Layer-3 gather: 8 lanes/node, lane owns 1 channel; weights computed inline.
// ---------------------------------------------------------------------------
__global__ void gather_l3(const int* __restrict__ elist, const int* __restrict__ offsets,
                          const float* __restrict__ s3, const float* __restrict__ d3,
                          const __hip_bfloat16* __restrict__ h,
                          const float* __restrict__ b,
                          __hip_bfloat16* __restrict__ act) {
    int gid = blockIdx.x * blockDim.x + threadIdx.x;
    if (gid >= NN * 8) return;
    int node = gid >> 3, t = gid & 7;
    int j0 = offsets[node], j1 = offsets[node + 1];
    float dnode = d3[node];
    float den = 0.f, acc = 0.f;
    const unsigned short* hp = (const unsigned short*)h + t;
    int j = j0;
    for (; j + 4 <= j1; j += 4) {
        int sA = elist[j], sB = elist[j+1], sC = elist[j+2], sD = elist[j+3];
        float wA = lrelu_exp(s3[sA] + dnode), wB = lrelu_exp(s3[sB] + dnode);
        float wC = lrelu_exp(s3[sC] + dnode), wD = lrelu_exp(s3[sD] + dnode);
        float xA = us2f(hp[(size_t)sA * 8]);
        float xB = us2f(hp[(size_t)sB * 8]);
        float xC = us2f(hp[(size_t)sC * 8]);
        float xD = us2f(hp[(size_t)sD * 8]);
        den += (wA + wB) + (wC + wD);
        acc += wA * xA + wB * xB + wC * xC + wD * xD;
    }
    for (; j < j1; j++) {
        int sE = elist[j];
        float w = lrelu_exp(s3[sE] + dnode);
        den += w;
        acc += w * us2f(hp[(size_t)sE * 8]);
    }
    float v = acc / den + b[t];
    v = v > 0.f ? v : (__expf(v) - 1.0f);
    act[(size_t)node * 8 + t] = __float2bfloat16(v);
}

// ---------------------------------------------------------------------------
// Final edge MLP: z[19] = [h3[src], h3[dst], ea, yr, qt] -> fc1(relu) -> fc2
// ---------------------------------------------------------------------------
__global__ void mlp_kernel(const int* __restrict__ ei,
                           const __hip_bfloat16* __restrict__ act3,
                           const float* __restrict__ ea,
                           const float* __restrict__ yr,
                           const float* __restrict__ qt,
                           const float* __restrict__ fc1w,
                           const float* __restrict__ fc1b,
                           const float* __restrict__ fc2w,
                           const float* __restrict__ fc2b,
                           float* __restrict__ outp) {
    __shared__ float w1[16 * 19], b1s[16], w2[16];
    for (int i = threadIdx.x; i < 16 * 19; i += blockDim.x) w1[i] = fc1w[i];
    if (threadIdx.x < 16) {
        b1s[threadIdx.x] = fc1b[threadIdx.x];
        w2[threadIdx.x] = fc2w[threadIdx.x];
    }
    __syncthreads();
    int e = blockIdx.x * blockDim.x + threadIdx.x;
    if (e >= EE) return;
    int src = ei[e], dst = ei[EE + e];
    short8 hs = *(const short8*)(act3 + (size_t)src * 8);
    short8 hd = *(const short8*)(act3 + (size_t)dst * 8);
    float z[19];
#pragma unroll
    for (int i = 0; i < 8; i++) z[i] = us2f((unsigned short)hs[i]);
#pragma unroll
    for (int i = 0; i < 8; i++) z[8 + i] = us2f((unsigned short)hd[i]);
    z[16] = ea[e]; z[17] = yr[e]; z[18] = qt[e];
    float acc2 = fc2b[0];
#pragma unroll
    for (int j = 0; j < 16; j++) {
        float a = b1s[j];
#pragma unroll
        for (int i = 0; i < 19; i++) a += z[i] * w1[j * 19 + i];
        a = a > 0.f ? a : 0.f;
        acc2 += a * w2[j];
    }
    outp[e] = acc2;
}

// ---------------------------------------------------------------------------
extern "C" void kernel_launch(void* const* d_in, const int* in_sizes, int n_in,
                              void* d_out, int out_size, void* d_ws, size_t ws_size,
                              hipStream_t stream) {
    const float* x    = (const float*)d_in[0];
    const int*   ei   = (const int*)d_in[1];
    const float* ea   = (const float*)d_in[2];
    const float* yr   = (const float*)d_in[3];
    const float* qt   = (const float*)d_in[4];
    const float* W1   = (const float*)d_in[5];
    const float* a1s  = (const float*)d_in[6];
    const float* a1d  = (const float*)d_in[7];
    const float* b1   = (const float*)d_in[8];
    const float* W2   = (const float*)d_in[9];
    const float* a2s  = (const float*)d_in[10];
    const float* a2d  = (const float*)d_in[11];
    const float* b2   = (const float*)d_in[12];
    const float* W3   = (const float*)d_in[13];
    const float* a3s  = (const float*)d_in[14];
    const float* a3d  = (const float*)d_in[15];
    const float* b3   = (const float*)d_in[16];
    const float* fc1w = (const float*)d_in[17];
    const float* fc1b = (const float*)d_in[18];
    const float* fc2w = (const float*)d_in[19];
    const float* fc2b = (const float*)d_in[20];
    float* outp = (float*)d_out;

    char* ws = (char*)d_ws;
    __hip_bfloat16* h_buf   = (__hip_bfloat16*)(ws);                 // N*512 bf16: h3
    __hip_bfloat16* act_buf = (__hip_bfloat16*)(ws + 51200000);      // N*512 bf16: xb / act3
    float* s_buf   = (float*)(ws + 102400000);                       // N*4 f32: s1/s2
    float* d_buf   = (float*)(ws + 103200000);                       // N*4 f32: d1/d2
    int*   deg     = (int*)  (ws + 104000000);                       // N ints
    int*   cursor  = (int*)  (ws + 104200000);                       // N ints (contiguous w/ deg)
    int*   offsets = (int*)  (ws + 104400000);                       // N+1 ints
    int*   elist   = (int*)  (ws + 104600016);                       // EP ints (1.8 MB)
    __hip_bfloat16* pw1 = (__hip_bfloat16*)(ws + 106400016);         // 512*128 bf16 packed
    __hip_bfloat16* pw2 = (__hip_bfloat16*)(ws + 106531088);         // 128*512 bf16 packed
    float* usd  = (float*)(ws + 106662160);                          // 8*128 f32 (4 KB)
    int*   bsum = (int*)  (ws + 106666256);                          // SCB ints
    float* welist = (float*)(ws + 106666512);                        // EP*4 f32 (7.2 MB), layer-1 only
    float* s3_buf = (float*)(ws + 113866512);                        // N f32
    float* d3_buf = (float*)(ws + 114071312);                        // N f32
    __hip_bfloat16* h2_buf = (__hip_bfloat16*)(ws + 114276112);      // N*128 bf16 (12.8 MB)
    __hip_bfloat16* xb = act_buf;                                    // N*128 bf16, dead after l1_fused

    // ---- prep (deg + weight pack + usd) + CSR scan ----
    hipMemsetAsync(deg, 0, 2 * NN * sizeof(int), stream);            // deg + cursor
    prep_kernel<<<DEGB + CVTB + 4, 256, 0, stream>>>(ei, deg, W1, W2, pw1, pw2, a1s, a1d, usd);
    scan1_kernel<<<SCB, 256, 0, stream>>>(deg, bsum);
    scan2_kernel<<<SCB, 256, 0, stream>>>(deg, bsum, offsets);
    cvtx_sd<<<(NN + 63) / 64, 256, 0, stream>>>(x, usd, xb, s_buf, d_buf, NN);
    fill_kernel<<<(EP + 255) / 256, 256, 0, stream>>>(ei, offsets, cursor, s_buf, d_buf,
                                                      elist, welist);

    // ---- Layers 1+2 fused: gather + bdiag GEMM (LDS) + l2 GEMM -> h2, s2/d2 ----
    l1_fused<<<NN / 16, 512, 0, stream>>>(elist, offsets, welist, xb, pw1, b1,
                                          pw2, a2s, a2d, h2_buf, s_buf, d_buf);

    // ---- Layer-2 gather (inline w) fused with layer-3 GEMM -> h3, s3, d3 ----
    gather_l2_g8<<<(NN * 64 + 255) / 256, 256, 0, stream>>>(
        elist, offsets, s_buf, d_buf, h2_buf, b2, W3, a3s, a3d,
        h_buf, s3_buf, d3_buf);

    // ---- Layer 3: gather (inline w) -> act3 in act_buf ----
    gather_l3<<<(NN * 8 + 255) / 256, 256, 0, stream>>>(
        elist, offsets, s3_buf, d3_buf, h_buf, b3, act_buf);

    // ---- Final edge MLP ----
    mlp_kernel<<<(EE + 255) / 256, 256, 0, stream>>>(ei, act_buf, ea, yr, qt,
                                                     fc1w, fc1b, fc2w, fc2b, outp);
}

// Round 17
// 269.475 us; speedup vs baseline: 1.0157x; 1.0157x over previous
//
#include <hip/hip_runtime.h>
#include <hip/hip_bf16.h>

#define NN 50000
#define EE 400000
#define EP 450000   // EE + NN self-loops

typedef __attribute__((ext_vector_type(8))) short short8;
typedef __attribute__((ext_vector_type(4))) float f32x4;
typedef __attribute__((ext_vector_type(2))) float f32x2;

__device__ __forceinline__ float us2f(unsigned short u) {
    unsigned int x = ((unsigned int)u) << 16;
    union { unsigned int i; float f; } c; c.i = x; return c.f;
}
__device__ __forceinline__ unsigned short f2bfu(float f) {   // f32 -> bf16 bits, RNE
    union { float f; unsigned int u; } c; c.f = f;
    unsigned int r = c.u + 0x7FFFu + ((c.u >> 16) & 1u);
    return (unsigned short)(r >> 16);
}
__device__ __forceinline__ unsigned int pack2bf(float lo, float hi) {
    return (unsigned int)f2bfu(lo) | ((unsigned int)f2bfu(hi) << 16);
}
__device__ __forceinline__ float lrelu_exp(float x) {
    x = x > 0.f ? x : 0.2f * x;
    return __expf(x);
}

// Packed MFMA-fragment index for a [M x K] bf16 matrix consumed as A (or B with
// n in place of m) by mfma_f32_16x16x32_bf16:
//   idx(m,k) = ((m>>4)*(K/32) + (k>>5))*512 + ((k&31)>>3)*128 + (m&15)*8 + (k&7)

// ---------------------------------------------------------------------------
// prep: fused deg histogram + W1/W2 f32->bf16 packed convert + usd precompute.
// ---------------------------------------------------------------------------
#define DEGB 1758
#define CVTB 512
__global__ void prep_kernel(const int* __restrict__ ei, int* __restrict__ deg,
                            const float* __restrict__ W1, const float* __restrict__ W2,
                            __hip_bfloat16* __restrict__ pw1, __hip_bfloat16* __restrict__ pw2,
                            const float* __restrict__ a1s, const float* __restrict__ a1d,
                            float* __restrict__ usd) {
    int b = blockIdx.x;
    if (b < DEGB) {
        int e = b * 256 + threadIdx.x;
        if (e >= EP) return;
        int dst = (e < EE) ? ei[EE + e] : e - EE;
        atomicAdd(&deg[dst], 1);
    } else if (b < DEGB + CVTB) {
        int i = (b - DEGB) * 256 + threadIdx.x;
        if (i < 65536) {
            int n = i >> 7, k = i & 127;   // K=128, NK=4
            int idx = ((n >> 4) * 4 + (k >> 5)) * 512 + ((k & 31) >> 3) * 128 + (n & 15) * 8 + (k & 7);
            pw1[idx] = __float2bfloat16(W1[i]);
        } else {
            int j = i - 65536;
            int n = j >> 9, k = j & 511;   // K=512, NK=16
            int idx = ((n >> 4) * 16 + (k >> 5)) * 512 + ((k & 31) >> 3) * 128 + (n & 15) * 8 + (k & 7);
            pw2[idx] = __float2bfloat16(W2[j]);
        }
    } else {
        int t = (b - DEGB - CVTB) * 256 + threadIdx.x;
        if (t >= 1024) return;
        int row = t >> 7, k = t & 127;
        int hh = row & 3;
        const float* av = (row < 4) ? (a1s + hh * 128) : (a1d + hh * 128);
        const float* wp = W1 + (size_t)(hh * 128) * 128 + k;
        float acc = 0.f;
        for (int c = 0; c < 128; c++) acc += av[c] * wp[(size_t)c * 128];
        usd[t] = acc;
    }
}

// ---------------------------------------------------------------------------
// Fused: x (f32) -> xb (bf16) convert + s1/d1 = x . usd.
// ---------------------------------------------------------------------------
__global__ void cvtx_sd(const float* __restrict__ x, const float* __restrict__ usd,
                        __hip_bfloat16* __restrict__ xb,
                        float* __restrict__ s, float* __restrict__ d, int M) {
    __shared__ float us_s[1024];
    for (int i = threadIdx.x; i < 1024; i += 256) us_s[i] = usd[i];
    __syncthreads();
    int wave = threadIdx.x >> 6, lane = threadIdx.x & 63;
    int m0 = blockIdx.x * 64 + wave * 16;
    int r = lane & 15, quad = lane >> 4;
    int am = m0 + r; if (am >= M) am = M - 1;
    const float* xp = x + (size_t)am * 128 + quad * 8;
    float xv[32];
#pragma unroll
    for (int kk = 0; kk < 4; kk++) {
        float4 a = *(const float4*)(xp + kk * 32);
        float4 bq = *(const float4*)(xp + kk * 32 + 4);
        xv[kk*8+0]=a.x;  xv[kk*8+1]=a.y;  xv[kk*8+2]=a.z;  xv[kk*8+3]=a.w;
        xv[kk*8+4]=bq.x; xv[kk*8+5]=bq.y; xv[kk*8+6]=bq.z; xv[kk*8+7]=bq.w;
        short8 o;
        o[0]=(short)f2bfu(a.x);  o[1]=(short)f2bfu(a.y);
        o[2]=(short)f2bfu(a.z);  o[3]=(short)f2bfu(a.w);
        o[4]=(short)f2bfu(bq.x); o[5]=(short)f2bfu(bq.y);
        o[6]=(short)f2bfu(bq.z); o[7]=(short)f2bfu(bq.w);
        *(short8*)(xb + (size_t)am * 128 + quad * 8 + kk * 32) = o;
    }
    float acc[8];
#pragma unroll
    for (int o = 0; o < 8; o++) {
        const float* up = us_s + o * 128 + quad * 8;
        float a = 0.f;
#pragma unroll
        for (int kk = 0; kk < 4; kk++)
#pragma unroll
            for (int j = 0; j < 8; j++) a += xv[kk*8+j] * up[kk*32+j];
        acc[o] = a;
    }
#pragma unroll
    for (int o = 0; o < 8; o++) {
        acc[o] += __shfl_xor(acc[o], 16, 64);
        acc[o] += __shfl_xor(acc[o], 32, 64);
    }
    int m = m0 + r;
    if (quad == 0 && m < M) {
#pragma unroll
        for (int hh = 0; hh < 4; hh++) { s[m*4+hh] = acc[hh]; d[m*4+hh] = acc[4+hh]; }
    }
}

// ---------------------------------------------------------------------------
// Two-level multi-block scan of deg -> offsets
// ---------------------------------------------------------------------------
#define SCB 49
__global__ void scan1_kernel(const int* __restrict__ deg, int* __restrict__ bsum) {
    __shared__ int red[256];
    int b = blockIdx.x, t = threadIdx.x;
    int base = b * 1024 + t * 4;
    int s = 0;
    if (base + 3 < NN) { int4 v = *(const int4*)(deg + base); s = v.x + v.y + v.z + v.w; }
    else { for (int i = base; i < NN; i++) s += deg[i]; }
    red[t] = s;
    __syncthreads();
    for (int off = 128; off > 0; off >>= 1) {
        if (t < off) red[t] += red[t + off];
        __syncthreads();
    }
    if (t == 0) bsum[b] = red[0];
}

__global__ void scan2_kernel(const int* __restrict__ deg, const int* __restrict__ bsum,
                             int* __restrict__ offsets) {
    __shared__ int lsum[256];
    int b = blockIdx.x, t = threadIdx.x;
    int boff = 0;
    for (int i = 0; i < b; i++) boff += bsum[i];
    int base = b * 1024 + t * 4;
    int4 v = {0, 0, 0, 0};
    if (base + 3 < NN) v = *(const int4*)(deg + base);
    else {
        if (base < NN)     v.x = deg[base];
        if (base + 1 < NN) v.y = deg[base + 1];
        if (base + 2 < NN) v.z = deg[base + 2];
        if (base + 3 < NN) v.w = deg[base + 3];
    }
    int s = v.x + v.y + v.z + v.w;
    lsum[t] = s;
    __syncthreads();
    for (int off = 1; off < 256; off <<= 1) {
        int val = (t >= off) ? lsum[t - off] : 0;
        __syncthreads();
        lsum[t] += val;
        __syncthreads();
    }
    int ex = boff + (t ? lsum[t - 1] : 0);
    if (base < NN)     offsets[base]     = ex;
    if (base + 1 < NN) offsets[base + 1] = ex + v.x;
    if (base + 2 < NN) offsets[base + 2] = ex + v.x + v.y;
    if (base + 3 < NN) offsets[base + 3] = ex + v.x + v.y + v.z;
    if (b == SCB - 1 && t == 255) offsets[NN] = boff + lsum[255];
}

// ---------------------------------------------------------------------------
// fill: CSR scatter + fused layer-1 edge weights (s1/d1 already computed).
// ---------------------------------------------------------------------------
__global__ void fill_kernel(const int* __restrict__ ei, const int* __restrict__ offsets,
                            int* __restrict__ cursor,
                            const float* __restrict__ s1, const float* __restrict__ d1,
                            int* __restrict__ elist, float* __restrict__ welist) {
    int e = blockIdx.x * blockDim.x + threadIdx.x;
    if (e >= EP) return;
    int src, dst;
    if (e < EE) { src = ei[e]; dst = ei[EE + e]; } else { src = dst = e - EE; }
    int pos = atomicAdd(&cursor[dst], 1);
    int j = offsets[dst] + pos;
    elist[j] = src;
    float4 sv = *(const float4*)(s1 + (size_t)src * 4);
    float4 dv = *(const float4*)(d1 + (size_t)dst * 4);
    float4 w;
    w.x = lrelu_exp(sv.x + dv.x);
    w.y = lrelu_exp(sv.y + dv.y);
    w.z = lrelu_exp(sv.z + dv.z);
    w.w = lrelu_exp(sv.w + dv.w);
    *(float4*)(welist + (size_t)j * 4) = w;
}

// ---------------------------------------------------------------------------
// Edge accumulate, packed over HEAD PAIRS (w01 = heads 0-1, w23 = heads 2-3):
// acc[0]=c0/h01, acc[1]=c0/h23, acc[2]=c1/h01, acc[3]=c1/h23.
// Plain vector C — clang emits v_pk_fma_f32 / v_pk_add_f32 on gfx950.
// ---------------------------------------------------------------------------
__device__ __forceinline__ void acc_edge(f32x2& den01, f32x2& den23, f32x2 (&acc)[4],
                                         float4 w, unsigned int x) {
    float x0 = us2f((unsigned short)x), x1 = us2f((unsigned short)(x >> 16));
    f32x2 w01; w01[0] = w.x; w01[1] = w.y;
    f32x2 w23; w23[0] = w.z; w23[1] = w.w;
    f32x2 x0s; x0s[0] = x0; x0s[1] = x0;
    f32x2 x1s; x1s[0] = x1; x1s[1] = x1;
    acc[0] += w01 * x0s;
    acc[1] += w23 * x0s;
    acc[2] += w01 * x1s;
    acc[3] += w23 * x1s;
    den01 += w01;
    den23 += w23;
}

// ---------------------------------------------------------------------------
// Layer-1+2 FUSED: gather + bdiag GEMM (LDS) + layer-2 GEMM. 512 thr = 8 waves.
// LDS: ONE 16.6 KB buffer. act1 ALIASES frag (in-place reuse, race-free via
// an extra barrier between afrag register loads and act1 writes).
// ---------------------------------------------------------------------------
__global__ void l1_fused(
        const int* __restrict__ elist, const int* __restrict__ offsets,
        const float* __restrict__ wl,
        const __hip_bfloat16* __restrict__ xb,
        const __hip_bfloat16* __restrict__ pW1,
        const float* __restrict__ b,
        const __hip_bfloat16* __restrict__ pW2,
        const float* __restrict__ as_, const float* __restrict__ ad_,
        __hip_bfloat16* __restrict__ h2,
        float* __restrict__ s2, float* __restrict__ d2) {
    __shared__ unsigned short frag[16 * 520];          // 16.6 KB (act1 aliases)
    unsigned short* act1 = frag;
    int w = threadIdx.x >> 6, lane = threadIdx.x & 63;
    int m0 = blockIdx.x * 16;

    // ---- phase 0: degree-sorted pairing (redundant per wave, no barrier) ----
    int li = lane < 16 ? lane : 15;
    int mydeg = offsets[m0 + li + 1] - offsets[m0 + li];
    int rank = 0;
#pragma unroll
    for (int jj = 0; jj < 16; jj++) {
        int od = __shfl(mydeg, jj, 64);
        rank += (od < mydeg) || (od == mydeg && jj < li);
    }
    unsigned long long balA = __ballot(lane < 16 && rank == w);
    unsigned long long balB = __ballot(lane < 16 && rank == 15 - w);
    int iA = (int)__builtin_ctzll(balA);
    int iB = (int)__builtin_ctzll(balB);
    int nodeA = m0 + iA, nodeB = m0 + iB;

    int ja  = __builtin_amdgcn_readfirstlane(offsets[nodeA]);
    int jA1 = __builtin_amdgcn_readfirstlane(offsets[nodeA + 1]);
    int jb  = __builtin_amdgcn_readfirstlane(offsets[nodeB]);
    int jB1 = __builtin_amdgcn_readfirstlane(offsets[nodeB + 1]);

    f32x2 dA01, dA23, dB01, dB23;
    dA01[0]=0.f; dA01[1]=0.f; dA23[0]=0.f; dA23[1]=0.f;
    dB01[0]=0.f; dB01[1]=0.f; dB23[0]=0.f; dB23[1]=0.f;
    f32x2 aA[4], aB[4];
#pragma unroll
    for (int h = 0; h < 4; h++) {
        aA[h][0]=0.f; aA[h][1]=0.f;
        aB[h][0]=0.f; aB[h][1]=0.f;
    }
    const unsigned short* xp = (const unsigned short*)xb + lane * 2;
    const float4* wl4 = (const float4*)wl;

    // 4+4 deep-pipelined main loop: 8 x-loads in flight
    while (ja + 4 <= jA1 && jb + 4 <= jB1) {
        int sA0 = elist[ja],   sA1 = elist[ja+1], sA2 = elist[ja+2], sA3 = elist[ja+3];
        int sB0 = elist[jb],   sB1 = elist[jb+1], sB2 = elist[jb+2], sB3 = elist[jb+3];
        float4 wA0 = wl4[ja],   wA1 = wl4[ja+1], wA2 = wl4[ja+2], wA3 = wl4[ja+3];
        float4 wB0 = wl4[jb],   wB1 = wl4[jb+1], wB2 = wl4[jb+2], wB3 = wl4[jb+3];
        unsigned int xA0 = *(const unsigned int*)(xp + (size_t)sA0 * 128);
        unsigned int xA1 = *(const unsigned int*)(xp + (size_t)sA1 * 128);
        unsigned int xA2 = *(const unsigned int*)(xp + (size_t)sA2 * 128);
        unsigned int xA3 = *(const unsigned int*)(xp + (size_t)sA3 * 128);
        unsigned int xB0 = *(const unsigned int*)(xp + (size_t)sB0 * 128);
        unsigned int xB1 = *(const unsigned int*)(xp + (size_t)sB1 * 128);
        unsigned int xB2 = *(const unsigned int*)(xp + (size_t)sB2 * 128);
        unsigned int xB3 = *(const unsigned int*)(xp + (size_t)sB3 * 128);
        acc_edge(dA01, dA23, aA, wA0, xA0); acc_edge(dA01, dA23, aA, wA1, xA1);
        acc_edge(dA01, dA23, aA, wA2, xA2); acc_edge(dA01, dA23, aA, wA3, xA3);
        acc_edge(dB01, dB23, aB, wB0, xB0); acc_edge(dB01, dB23, aB, wB1, xB1);
        acc_edge(dB01, dB23, aB, wB2, xB2); acc_edge(dB01, dB23, aB, wB3, xB3);
        ja += 4; jb += 4;
    }
    // 2+2 drain
    while (ja + 2 <= jA1 && jb + 2 <= jB1) {
        int sA0 = elist[ja], sA1 = elist[ja + 1];
        int sB0 = elist[jb], sB1 = elist[jb + 1];
        float4 wA0 = wl4[ja], wA1 = wl4[ja + 1];
        float4 wB0 = wl4[jb], wB1 = wl4[jb + 1];
        unsigned int xA0 = *(const unsigned int*)(xp + (size_t)sA0 * 128);
        unsigned int xA1 = *(const unsigned int*)(xp + (size_t)sA1 * 128);
        unsigned int xB0 = *(const unsigned int*)(xp + (size_t)sB0 * 128);
        unsigned int xB1 = *(const unsigned int*)(xp + (size_t)sB1 * 128);
        acc_edge(dA01, dA23, aA, wA0, xA0); acc_edge(dA01, dA23, aA, wA1, xA1);
        acc_edge(dB01, dB23, aB, wB0, xB0); acc_edge(dB01, dB23, aB, wB1, xB1);
        ja += 2; jb += 2;
    }
    while (ja + 2 <= jA1) {
        int sA0 = elist[ja], sA1 = elist[ja + 1];
        float4 wA0 = wl4[ja], wA1 = wl4[ja + 1];
        unsigned int xA0 = *(const unsigned int*)(xp + (size_t)sA0 * 128);
        unsigned int xA1 = *(const unsigned int*)(xp + (size_t)sA1 * 128);
        acc_edge(dA01, dA23, aA, wA0, xA0); acc_edge(dA01, dA23, aA, wA1, xA1);
        ja += 2;
    }
    while (jb + 2 <= jB1) {
        int sB0 = elist[jb], sB1 = elist[jb + 1];
        float4 wB0 = wl4[jb], wB1 = wl4[jb + 1];
        unsigned int xB0 = *(const unsigned int*)(xp + (size_t)sB0 * 128);
        unsigned int xB1 = *(const unsigned int*)(xp + (size_t)sB1 * 128);
        acc_edge(dB01, dB23, aB, wB0, xB0); acc_edge(dB01, dB23, aB, wB1, xB1);
        jb += 2;
    }
    if (ja < jA1) {
        int sA0 = elist[ja]; float4 wA0 = wl4[ja];
        unsigned int xA0 = *(const unsigned int*)(xp + (size_t)sA0 * 128);
        acc_edge(dA01, dA23, aA, wA0, xA0);
    }
    if (jb < jB1) {
        int sB0 = elist[jb]; float4 wB0 = wl4[jb];
        unsigned int xB0 = *(const unsigned int*)(xp + (size_t)sB0 * 128);
        acc_edge(dB01, dB23, aB, wB0, xB0);
    }

    // store both nodes' normalized fragments to LDS (swizzled)
    // acc layout: [0]=c0/h01 [1]=c0/h23 [2]=c1/h01 [3]=c1/h23
    {
        int c0 = lane * 2;
        int fq = c0 >> 5;
        int sub = (c0 & 31) >> 3;
        unsigned int* f32p = (unsigned int*)frag;
        int base0 = fq * 260 + sub * 64 + (c0 & 7) / 2;   // uint units
        {
            int rowp = iA ^ (sub << 2);
            int base = base0 + rowp * 4;
            float i0 = 1.f/dA01[0], i1 = 1.f/dA01[1], i2 = 1.f/dA23[0], i3 = 1.f/dA23[1];
            f32p[base]            = pack2bf(aA[0][0]*i0, aA[2][0]*i0);   // head0: c0,c1
            f32p[base + 4 * 260]  = pack2bf(aA[0][1]*i1, aA[2][1]*i1);   // head1
            f32p[base + 8 * 260]  = pack2bf(aA[1][0]*i2, aA[3][0]*i2);   // head2
            f32p[base + 12 * 260] = pack2bf(aA[1][1]*i3, aA[3][1]*i3);   // head3
        }
        {
            int rowp = iB ^ (sub << 2);
            int base = base0 + rowp * 4;
            float i0 = 1.f/dB01[0], i1 = 1.f/dB01[1], i2 = 1.f/dB23[0], i3 = 1.f/dB23[1];
            f32p[base]            = pack2bf(aB[0][0]*i0, aB[2][0]*i0);
            f32p[base + 4 * 260]  = pack2bf(aB[0][1]*i1, aB[2][1]*i1);
            f32p[base + 8 * 260]  = pack2bf(aB[1][0]*i2, aB[3][0]*i2);
            f32p[base + 12 * 260] = pack2bf(aB[1][1]*i3, aB[3][1]*i3);
        }
    }
    __syncthreads();

    // ---- phase 2: block-diagonal GEMM from LDS -> act1 IN PLACE ----
    int hh = w >> 1, half = w & 1;
    int r = lane & 15, quad = lane >> 4;
    int lsub = lane >> 4, lrow = lane & 15;
    int prow = lrow ^ (lsub << 2);
    {
        const unsigned short* fb = frag + lsub * 128 + prow * 8;
        short8 afrag[4];
#pragma unroll
        for (int kk = 0; kk < 4; kk++)
            afrag[kk] = *(const short8*)(fb + (hh * 4 + kk) * 520);
        __syncthreads();   // all afrag loads done before in-place act1 writes
#pragma unroll
        for (int t = 0; t < 4; t++) {
            int nb = half * 64 + t * 16;
            const __hip_bfloat16* bp = pW1 + ((size_t)(hh * 8 + (nb >> 4)) * 4) * 512 + lane * 8;
            f32x4 acc = {0.f, 0.f, 0.f, 0.f};
#pragma unroll
            for (int kk = 0; kk < 4; kk++) {
                short8 bfr = *(const short8*)(bp + kk * 512);
                acc = __builtin_amdgcn_mfma_f32_16x16x32_bf16(afrag[kk], bfr, acc, 0, 0, 0);
            }
            int n0 = hh * 128 + nb;
            float bias = b[n0 + r];
            int kk2 = (n0 + r) >> 5;                 // k-tile in K=512 layout
            int sub2 = ((nb & 16) + r) >> 3;         // k-subgroup
#pragma unroll
            for (int i = 0; i < 4; i++) {
                float v = acc[i] + bias;
                v = v > 0.f ? v : (__expf(v) - 1.0f);
                int rowp2 = (quad * 4 + i) ^ (sub2 << 2);
                act1[kk2 * 520 + sub2 * 128 + rowp2 * 8 + (r & 7)] = f2bfu(v);
            }
        }
    }
    __syncthreads();

    // ---- phase 3: layer-2 GEMM from act1 LDS (waves 0-3, wave = head) ----
    if (w < 4) {
        int h2h = w;                                 // head 0..3
        const __hip_bfloat16* bp0 = pW2 + (size_t)(h2h * 2) * 16 * 512 + lane * 8;
        const __hip_bfloat16* bp1 = bp0 + 16 * 512;
        const unsigned short* ab = act1 + lsub * 128 + prow * 8;
        f32x4 acc0 = {0.f, 0.f, 0.f, 0.f}, acc1 = {0.f, 0.f, 0.f, 0.f};
#pragma unroll
        for (int kk = 0; kk < 16; kk++) {
            short8 af = *(const short8*)(ab + kk * 520);
            short8 b0 = *(const short8*)(bp0 + kk * 512);
            short8 b1 = *(const short8*)(bp1 + kk * 512);
            acc0 = __builtin_amdgcn_mfma_f32_16x16x32_bf16(af, b0, acc0, 0, 0, 0);
            acc1 = __builtin_amdgcn_mfma_f32_16x16x32_bf16(af, b1, acc1, 0, 0, 0);
        }
        int n0 = h2h * 32;
        float as0 = as_[n0 + r],      ad0 = ad_[n0 + r];
        float as1 = as_[n0 + 16 + r], ad1 = ad_[n0 + 16 + r];
        float sacc[4], dacc[4];
#pragma unroll
        for (int i = 0; i < 4; i++) {
            int m = m0 + quad * 4 + i;
            h2[(size_t)m * 128 + n0 + r]      = __float2bfloat16(acc0[i]);
            h2[(size_t)m * 128 + n0 + 16 + r] = __float2bfloat16(acc1[i]);
            sacc[i] = acc0[i] * as0 + acc1[i] * as1;
            dacc[i] = acc0[i] * ad0 + acc1[i] * ad1;
        }
#pragma unroll
        for (int mask = 1; mask <= 8; mask <<= 1) {
#pragma unroll
            for (int i = 0; i < 4; i++) {
                sacc[i] += __shfl_xor(sacc[i], mask, 64);
                dacc[i] += __shfl_xor(dacc[i], mask, 64);
            }
        }
        if (r == 0) {
#pragma unroll
            for (int i = 0; i < 4; i++) {
                int m = m0 + quad * 4 + i;
                s2[m * 4 + h2h] = sacc[i]; d2[m * 4 + h2h] = dacc[i];
            }
        }
    }
}

// ---------------------------------------------------------------------------
// Layer-2 gather FUSED with layer-3 GEMM: node-per-wave; lane owns 2 h2
// channels. Edge weights INLINE from s2/d2. 8-DEEP edge pipeline (whole
// average node in flight). L3 GEMM via recursive-halving reduce.
// ---------------------------------------------------------------------------
__global__ void gather_l2_g8(const int* __restrict__ elist, const int* __restrict__ offsets,
                             const float* __restrict__ s2, const float* __restrict__ d2,
                             const __hip_bfloat16* __restrict__ h,
                             const float* __restrict__ b,
                             const float* __restrict__ W3,
                             const float* __restrict__ a3s, const float* __restrict__ a3d,
                             __hip_bfloat16* __restrict__ h3,
                             float* __restrict__ s3, float* __restrict__ d3) {
    int gid = blockIdx.x * blockDim.x + threadIdx.x;
    if (gid >= NN * 64) return;
    int node = gid >> 6;
    int lane = gid & 63;
    int c0 = lane * 2;
    int hh = lane >> 4;
    int j0 = __builtin_amdgcn_readfirstlane(offsets[node]);
    int j1 = __builtin_amdgcn_readfirstlane(offsets[node + 1]);
    float dv = d2[node * 4 + hh];
    float den = 0.f, acc0 = 0.f, acc1 = 0.f;
    const unsigned short* hp = (const unsigned short*)h + c0;
    int j = j0;
    // 8-deep pipeline: 8 independent elist->s2/h2 chains in flight
    for (; j + 8 <= j1; j += 8) {
        int sA = elist[j],   sB = elist[j+1], sC = elist[j+2], sD = elist[j+3];
        int sE = elist[j+4], sF = elist[j+5], sG = elist[j+6], sH = elist[j+7];
        float eA = s2[sA*4+hh] + dv, eB = s2[sB*4+hh] + dv;
        float eC = s2[sC*4+hh] + dv, eD = s2[sD*4+hh] + dv;
        float eE = s2[sE*4+hh] + dv, eF = s2[sF*4+hh] + dv;
        float eG = s2[sG*4+hh] + dv, eH = s2[sH*4+hh] + dv;
        unsigned int vA = *(const unsigned int*)(hp + (size_t)sA * 128);
        unsigned int vB = *(const unsigned int*)(hp + (size_t)sB * 128);
        unsigned int vC = *(const unsigned int*)(hp + (size_t)sC * 128);
        unsigned int vD = *(const unsigned int*)(hp + (size_t)sD * 128);
        unsigned int vE = *(const unsigned int*)(hp + (size_t)sE * 128);
        unsigned int vF = *(const unsigned int*)(hp + (size_t)sF * 128);
        unsigned int vG = *(const unsigned int*)(hp + (size_t)sG * 128);
        unsigned int vH = *(const unsigned int*)(hp + (size_t)sH * 128);
        float wA = lrelu_exp(eA), wB = lrelu_exp(eB);
        float wC = lrelu_exp(eC), wD = lrelu_exp(eD);
        float wE = lrelu_exp(eE), wF = lrelu_exp(eF);
        float wG = lrelu_exp(eG), wH = lrelu_exp(eH);
        den += (wA + wB) + (wC + wD);
        den += (wE + wF) + (wG + wH);
        acc0 += wA * us2f((unsigned short)vA) + wB * us2f((unsigned short)vB)
              + wC * us2f((unsigned short)vC) + wD * us2f((unsigned short)vD);
        acc0 += wE * us2f((unsigned short)vE) + wF * us2f((unsigned short)vF)
              + wG * us2f((unsigned short)vG) + wH * us2f((unsigned short)vH);
        acc1 += wA * us2f((unsigned short)(vA >> 16)) + wB * us2f((unsigned short)(vB >> 16))
              + wC * us2f((unsigned short)(vC >> 16)) + wD * us2f((unsigned short)(vD >> 16));
        acc1 += wE * us2f((unsigned short)(vE >> 16)) + wF * us2f((unsigned short)(vF >> 16))
              + wG * us2f((unsigned short)(vG >> 16)) + wH * us2f((unsigned short)(vH >> 16));
    }
    for (; j + 4 <= j1; j += 4) {
        int sA = elist[j], sB = elist[j+1], sC = elist[j+2], sD = elist[j+3];
        float eA = s2[sA * 4 + hh] + dv, eB = s2[sB * 4 + hh] + dv;
        float eC = s2[sC * 4 + hh] + dv, eD = s2[sD * 4 + hh] + dv;
        unsigned int vA = *(const unsigned int*)(hp + (size_t)sA * 128);
        unsigned int vB = *(const unsigned int*)(hp + (size_t)sB * 128);
        unsigned int vC = *(const unsigned int*)(hp + (size_t)sC * 128);
        unsigned int vD = *(const unsigned int*)(hp + (size_t)sD * 128);
        float wA = lrelu_exp(eA), wB = lrelu_exp(eB);
        float wC = lrelu_exp(eC), wD = lrelu_exp(eD);
        den += (wA + wB) + (wC + wD);
        acc0 += wA * us2f((unsigned short)vA) + wB * us2f((unsigned short)vB)
              + wC * us2f((unsigned short)vC) + wD * us2f((unsigned short)vD);
        acc1 += wA * us2f((unsigned short)(vA >> 16)) + wB * us2f((unsigned short)(vB >> 16))
              + wC * us2f((unsigned short)(vC >> 16)) + wD * us2f((unsigned short)(vD >> 16));
    }
    for (; j < j1; j++) {
        int sE = elist[j];
        float ww = lrelu_exp(s2[sE * 4 + hh] + dv);
        unsigned int v = *(const unsigned int*)(hp + (size_t)sE * 128);
        den += ww;
        acc0 += ww * us2f((unsigned short)v);
        acc1 += ww * us2f((unsigned short)(v >> 16));
    }
    float inv = 1.0f / den;
    float v0 = acc0 * inv + b[c0];
    float v1 = acc1 * inv + b[c0 + 1];
    v0 = v0 > 0.f ? v0 : (__expf(v0) - 1.0f);
    v1 = v1 > 0.f ? v1 : (__expf(v1) - 1.0f);
    // fused layer-3 GEMM: partial over this lane's 2 channels
    float part[8];
#pragma unroll
    for (int c = 0; c < 8; c++) {
        float2 wv = *(const float2*)(W3 + c * 128 + c0);
        part[c] = v0 * wv.x + v1 * wv.y;
    }
    // recursive-halving reduce-scatter: 8 -> 4 -> 2 -> 1 values
    float t4[4];
#pragma unroll
    for (int i = 0; i < 4; i++) {
        float send = (lane & 32) ? part[i] : part[4 + i];
        float keep = (lane & 32) ? part[4 + i] : part[i];
        t4[i] = keep + __shfl_xor(send, 32, 64);
    }
    float t2[2];
#pragma unroll
    for (int i = 0; i < 2; i++) {
        float send = (lane & 16) ? t4[i] : t4[2 + i];
        float keep = (lane & 16) ? t4[2 + i] : t4[i];
        t2[i] = keep + __shfl_xor(send, 16, 64);
    }
    float gv;
    {
        float send = (lane & 8) ? t2[0] : t2[1];
        float keep = (lane & 8) ? t2[1] : t2[0];
        gv = keep + __shfl_xor(send, 8, 64);
    }
    gv += __shfl_xor(gv, 4, 64);
    gv += __shfl_xor(gv, 2, 64);
    gv += __shfl_xor(gv, 1, 64);
    int o = ((lane >> 5) & 1) * 4 + ((lane >> 4) & 1) * 2 + ((lane >> 3) & 1);
    if ((lane & 7) == 0) h3[(size_t)node * 8 + o] = __float2bfloat16(gv);
    // s3/d3: sum over the 8 groups (masks 8/16/32 only -> each group once)
    float cs = gv * a3s[o];
    float cd = gv * a3d[o];
    cs += __shfl_xor(cs, 8, 64);  cd += __shfl_xor(cd, 8, 64);
    cs += __shfl_xor(cs, 16, 64); cd += __shfl_xor(cd, 16, 64);
    cs += __shfl_xor(cs, 32, 64); cd += __shfl_xor(cd, 32, 64);
    if (lane == 0) { s3[node] = cs; d3[node] = cd; }
}

// ---------------------------------------------------------------------------
// Layer-3 gather: 8 lanes/node, lane owns 1 channel; weights inline; 8-deep.
// ---------------------------------------------------------------------------
__global__ void gather_l3(const int* __restrict__ elist, const int* __restrict__ offsets,
                          const float* __restrict__ s3, const float* __restrict__ d3,
                          const __hip_bfloat16* __restrict__ h,
                          const float* __restrict__ b,
                          __hip_bfloat16* __restrict__ act) {
    int gid = blockIdx.x * blockDim.x + threadIdx.x;
    if (gid >= NN * 8) return;
    int node = gid >> 3, t = gid & 7;
    int j0 = offsets[node], j1 = offsets[node + 1];
    float dnode = d3[node];
    float den = 0.f, acc = 0.f;
    const unsigned short* hp = (const unsigned short*)h + t;
    int j = j0;
    for (; j + 8 <= j1; j += 8) {
        int sA = elist[j],   sB = elist[j+1], sC = elist[j+2], sD = elist[j+3];
        int sE = elist[j+4], sF = elist[j+5], sG = elist[j+6], sH = elist[j+7];
        float wA = lrelu_exp(s3[sA] + dnode), wB = lrelu_exp(s3[sB] + dnode);
        float wC = lrelu_exp(s3[sC] + dnode), wD = lrelu_exp(s3[sD] + dnode);
        float wE = lrelu_exp(s3[sE] + dnode), wF = lrelu_exp(s3[sF] + dnode);
        float wG = lrelu_exp(s3[sG] + dnode), wH = lrelu_exp(s3[sH] + dnode);
        float xA = us2f(hp[(size_t)sA * 8]), xB = us2f(hp[(size_t)sB * 8]);
        float xC = us2f(hp[(size_t)sC * 8]), xD = us2f(hp[(size_t)sD * 8]);
        float xE = us2f(hp[(size_t)sE * 8]), xF = us2f(hp[(size_t)sF * 8]);
        float xG = us2f(hp[(size_t)sG * 8]), xH = us2f(hp[(size_t)sH * 8]);
        den += (wA + wB) + (wC + wD);
        den += (wE + wF) + (wG + wH);
        acc += wA * xA + wB * xB + wC * xC + wD * xD;
        acc += wE * xE + wF * xF + wG * xG + wH * xH;
    }
    for (; j + 4 <= j1; j += 4) {
        int sA = elist[j], sB = elist[j+1], sC = elist[j+2], sD = elist[j+3];
        float wA = lrelu_exp(s3[sA] + dnode), wB = lrelu_exp(s3[sB] + dnode);
        float wC = lrelu_exp(s3[sC] + dnode), wD = lrelu_exp(s3[sD] + dnode);
        float xA = us2f(hp[(size_t)sA * 8]);
        float xB = us2f(hp[(size_t)sB * 8]);
        float xC = us2f(hp[(size_t)sC * 8]);
        float xD = us2f(hp[(size_t)sD * 8]);
        den += (wA + wB) + (wC + wD);
        acc += wA * xA + wB * xB + wC * xC + wD * xD;
    }
    for (; j < j1; j++) {
        int sE = elist[j];
        float w = lrelu_exp(s3[sE] + dnode);
        den += w;
        acc += w * us2f(hp[(size_t)sE * 8]);
    }
    float v = acc / den + b[t];
    v = v > 0.f ? v : (__expf(v) - 1.0f);
    act[(size_t)node * 8 + t] = __float2bfloat16(v);
}

// ---------------------------------------------------------------------------
// Final edge MLP: z[19] = [h3[src], h3[dst], ea, yr, qt] -> fc1(relu) -> fc2
// ---------------------------------------------------------------------------
__global__ void mlp_kernel(const int* __restrict__ ei,
                           const __hip_bfloat16* __restrict__ act3,
                           const float* __restrict__ ea,
                           const float* __restrict__ yr,
                           const float* __restrict__ qt,
                           const float* __restrict__ fc1w,
                           const float* __restrict__ fc1b,
                           const float* __restrict__ fc2w,
                           const float* __restrict__ fc2b,
                           float* __restrict__ outp) {
    __shared__ float w1[16 * 19], b1s[16], w2[16];
    for (int i = threadIdx.x; i < 16 * 19; i += blockDim.x) w1[i] = fc1w[i];
    if (threadIdx.x < 16) {
        b1s[threadIdx.x] = fc1b[threadIdx.x];
        w2[threadIdx.x] = fc2w[threadIdx.x];
    }
    __syncthreads();
    int e = blockIdx.x * blockDim.x + threadIdx.x;
    if (e >= EE) return;
    int src = ei[e], dst = ei[EE + e];
    short8 hs = *(const short8*)(act3 + (size_t)src * 8);
    short8 hd = *(const short8*)(act3 + (size_t)dst * 8);
    float z[19];
#pragma unroll
    for (int i = 0; i < 8; i++) z[i] = us2f((unsigned short)hs[i]);
#pragma unroll
    for (int i = 0; i < 8; i++) z[8 + i] = us2f((unsigned short)hd[i]);
    z[16] = ea[e]; z[17] = yr[e]; z[18] = qt[e];
    float acc2 = fc2b[0];
#pragma unroll
    for (int j = 0; j < 16; j++) {
        float a = b1s[j];
#pragma unroll
        for (int i = 0; i < 19; i++) a += z[i] * w1[j * 19 + i];
        a = a > 0.f ? a : 0.f;
        acc2 += a * w2[j];
    }
    outp[e] = acc2;
}

// ---------------------------------------------------------------------------
extern "C" void kernel_launch(void* const* d_in, const int* in_sizes, int n_in,
                              void* d_out, int out_size, void* d_ws, size_t ws_size,
                              hipStream_t stream) {
    const float* x    = (const float*)d_in[0];
    const int*   ei   = (const int*)d_in[1];
    const float* ea   = (const float*)d_in[2];
    const float* yr   = (const float*)d_in[3];
    const float* qt   = (const float*)d_in[4];
    const float* W1   = (const float*)d_in[5];
    const float* a1s  = (const float*)d_in[6];
    const float* a1d  = (const float*)d_in[7];
    const float* b1   = (const float*)d_in[8];
    const float* W2   = (const float*)d_in[9];
    const float* a2s  = (const float*)d_in[10];
    const float* a2d  = (const float*)d_in[11];
    const float* b2   = (const float*)d_in[12];
    const float* W3   = (const float*)d_in[13];
    const float* a3s  = (const float*)d_in[14];
    const float* a3d  = (const float*)d_in[15];
    const float* b3   = (const float*)d_in[16];
    const float* fc1w = (const float*)d_in[17];
    const float* fc1b = (const float*)d_in[18];
    const float* fc2w = (const float*)d_in[19];
    const float* fc2b = (const float*)d_in[20];
    float* outp = (float*)d_out;

    char* ws = (char*)d_ws;
    __hip_bfloat16* h_buf   = (__hip_bfloat16*)(ws);                 // N*512 bf16: h3
    __hip_bfloat16* act_buf = (__hip_bfloat16*)(ws + 51200000);      // N*512 bf16: xb / act3
    float* s_buf   = (float*)(ws + 102400000);                       // N*4 f32: s1/s2
    float* d_buf   = (float*)(ws + 103200000);                       // N*4 f32: d1/d2
    int*   deg     = (int*)  (ws + 104000000);                       // N ints
    int*   cursor  = (int*)  (ws + 104200000);                       // N ints (contiguous w/ deg)
    int*   offsets = (int*)  (ws + 104400000);                       // N+1 ints
    int*   elist   = (int*)  (ws + 104600016);                       // EP ints (1.8 MB)
    __hip_bfloat16* pw1 = (__hip_bfloat16*)(ws + 106400016);         // 512*128 bf16 packed
    __hip_bfloat16* pw2 = (__hip_bfloat16*)(ws + 106531088);         // 128*512 bf16 packed
    float* usd  = (float*)(ws + 106662160);                          // 8*128 f32 (4 KB)
    int*   bsum = (int*)  (ws + 106666256);                          // SCB ints
    float* welist = (float*)(ws + 106666512);                        // EP*4 f32 (7.2 MB), layer-1 only
    float* s3_buf = (float*)(ws + 113866512);                        // N f32
    float* d3_buf = (float*)(ws + 114071312);                        // N f32
    __hip_bfloat16* h2_buf = (__hip_bfloat16*)(ws + 114276112);      // N*128 bf16 (12.8 MB)
    __hip_bfloat16* xb = act_buf;                                    // N*128 bf16, dead after l1_fused

    // ---- prep (deg + weight pack + usd) + CSR scan ----
    hipMemsetAsync(deg, 0, 2 * NN * sizeof(int), stream);            // deg + cursor
    prep_kernel<<<DEGB + CVTB + 4, 256, 0, stream>>>(ei, deg, W1, W2, pw1, pw2, a1s, a1d, usd);
    scan1_kernel<<<SCB, 256, 0, stream>>>(deg, bsum);
    scan2_kernel<<<SCB, 256, 0, stream>>>(deg, bsum, offsets);
    cvtx_sd<<<(NN + 63) / 64, 256, 0, stream>>>(x, usd, xb, s_buf, d_buf, NN);
    fill_kernel<<<(EP + 255) / 256, 256, 0, stream>>>(ei, offsets, cursor, s_buf, d_buf,
                                                      elist, welist);

    // ---- Layers 1+2 fused: gather + bdiag GEMM (LDS) + l2 GEMM -> h2, s2/d2 ----
    l1_fused<<<NN / 16, 512, 0, stream>>>(elist, offsets, welist, xb, pw1, b1,
                                          pw2, a2s, a2d, h2_buf, s_buf, d_buf);

    // ---- Layer-2 gather (inline w) fused with layer-3 GEMM -> h3, s3, d3 ----
    gather_l2_g8<<<(NN * 64 + 255) / 256, 256, 0, stream>>>(
        elist, offsets, s_buf, d_buf, h2_buf, b2, W3, a3s, a3d,
        h_buf, s3_buf, d3_buf);

    // ---- Layer 3: gather (inline w) -> act3 in act_buf ----
    gather_l3<<<(NN * 8 + 255) / 256, 256, 0, stream>>>(
        elist, offsets, s3_buf, d3_buf, h_buf, b3, act_buf);

    // ---- Final edge MLP ----
    mlp_kernel<<<(EE + 255) / 256, 256, 0, stream>>>(ei, act_buf, ea, yr, qt,
                                                     fc1w, fc1b, fc2w, fc2b, outp);
}